// Round 7
// baseline (800.648 us; speedup 1.0000x reference)
//
#include <hip/hip_runtime.h>
#include <math.h>

// ---------------------------------------------------------------------------
// B=256, T=256, LEN=256 (audio 64 | vision 64 | text 128), RANK=24, EXT=513
// xp gate tensors: [b][t][col][gate] (gate innermost). Wih rows permuted as
// n' = col*4 + gate so the dense GEMM epilogue IS the xp layout. Whh and xp
// are PRE-SCALED by -log2e (gates i,f,o) / -2log2e (gate g) so the recurrence
// uses bare v_exp_f32 (exp2) with no argument multiply.
// ---------------------------------------------------------------------------

typedef unsigned short ushortT;
typedef short bf16x8 __attribute__((ext_vector_type(8)));
typedef float f32x4 __attribute__((ext_vector_type(4)));
typedef float f32x2 __attribute__((ext_vector_type(2)));
typedef float f4u __attribute__((ext_vector_type(4), aligned(4)));

#define K1C (-1.4426950408889634f)  // -log2(e)
#define K2C (-2.885390081777927f)   // -2*log2(e)

__device__ __forceinline__ unsigned int f2bf(float f) {  // RNE to bf16
  unsigned int u = __float_as_uint(f);
  u += 0x7FFFu + ((u >> 16) & 1u);
  return u >> 16;
}
__device__ __forceinline__ unsigned int pk2bf(float lo, float hi) {
  return f2bf(lo) | (f2bf(hi) << 16);
}
__device__ __forceinline__ float bf2f(ushortT u) {
  return __uint_as_float(((unsigned int)u) << 16);
}
__device__ __forceinline__ float exp2i(float x) {  // bare v_exp_f32 (2^x)
  float r; asm("v_exp_f32 %0, %1" : "=v"(r) : "v"(x)); return r;
}
__device__ __forceinline__ unsigned int cvtbf(float x) {  // RNE bf16 in low16
  unsigned int r;
  asm("v_cvt_pk_bf16_f32 %0, %1, %2" : "=v"(r) : "v"(x), "v"(x));
  return r;
}

// ------------------- unified prep: weights cvt/permute/scale + zeroing ------
template <int KP, int KIN, int HR>  // HR!=0: row perm n' = col*4+gate
__device__ __forceinline__ void cvt_perm(const float* __restrict__ src,
                                         ushortT* __restrict__ dst,
                                         int i, int total) {
  if (i >= total) return;
  const int row = i / KP, c = i - row * KP;
  const int srow = HR ? ((row & 3) * HR + (row >> 2)) : row;
  const float v = (c < KIN) ? src[(size_t)srow * KIN + c] : 0.f;
  dst[i] = (ushortT)f2bf(v);
}
template <int GSH>  // Whh cvt with gate prescale; g = (i >> GSH) & 3
__device__ __forceinline__ void cvt_whh(const float* __restrict__ src,
                                        ushortT* __restrict__ dst,
                                        int i, int total) {
  if (i >= total) return;
  const int g = (i >> GSH) & 3;
  const float sc = (g == 2) ? K2C : K1C;
  dst[i] = (ushortT)f2bf(src[i] * sc);
}

__global__ __launch_bounds__(256) void prep_k(
    const float* __restrict__ Wih_t, const float* __restrict__ Whh_t,
    const float* __restrict__ Wih_a, const float* __restrict__ Whh_a,
    const float* __restrict__ Wih_v, const float* __restrict__ Whh_v,
    const float* __restrict__ W2,
    ushortT* __restrict__ Wt768, ushortT* __restrict__ WhhT16,
    ushortT* __restrict__ WA16, ushortT* __restrict__ WhhA16,
    ushortT* __restrict__ WV16, ushortT* __restrict__ WhhV16,
    float* __restrict__ w2a, float* __restrict__ w2b, float* __restrict__ w2c,
    float* __restrict__ s_acc, float* __restrict__ sumsq,
    unsigned int* __restrict__ cnt) {
  const int b = blockIdx.x, tid = threadIdx.x;
  if (b < 1536)       cvt_perm<768, 768, 128>(Wih_t, Wt768, b * 256 + tid, 393216);
  else if (b < 1792)  cvt_whh<14>(Whh_t, WhhT16, (b - 1536) * 256 + tid, 65536);
  else if (b < 1856)  cvt_whh<12>(Whh_a, WhhA16, (b - 1792) * 256 + tid, 16384);
  else if (b < 1920)  cvt_whh<12>(Whh_v, WhhV16, (b - 1856) * 256 + tid, 16384);
  else if (b < 2016)  cvt_perm<96, 74, 64>(Wih_a, WA16, (b - 1920) * 256 + tid, 24576);
  else if (b < 2080)  cvt_perm<64, 35, 64>(Wih_v, WV16, (b - 2016) * 256 + tid, 16384);
  else if (b < 2129) {  // W2 repack: [24][513] -> w2c | w2a[24][256] | w2b[24][256]
    const int i = (b - 2080) * 256 + tid;
    if (i < 12312) {
      const int dg = i / 513, c = i - dg * 513;
      const float v = W2[i];
      if (c == 0) w2c[dg] = v;
      else if (c <= 256) w2a[dg * 256 + c - 1] = v;
      else w2b[dg * 256 + c - 257] = v;
    }
  } else {  // zero accumulators + completion counter
    s_acc[tid] = 0.f;
    sumsq[tid] = 0.f;
    if (tid == 0) *cnt = 0u;
  }
}

// ---------------- text input projection GEMM (bf16 MFMA, 128x256) -----------
// xp = bf16( (X @ W16^T + bias) * gate_scale ); W16 rows pre-permuted
// gate-innermost. Register-prefetch: tile k+1's loads issued between the
// LDS-commit of tile k and the compute barrier.
#define SA2 40  // LDS row stride (BK=32 + 8 pad)
__global__ __launch_bounds__(512) void gemm_text2_k(const float* __restrict__ X,
                                                    const ushortT* __restrict__ W16,
                                                    const float* __restrict__ bias,
                                                    ushortT* __restrict__ Y16) {
  const int K = 768, N = 512;
  __shared__ __align__(16) ushortT As[128 * SA2];
  __shared__ __align__(16) ushortT Bs[256 * SA2];
  const unsigned int lin = blockIdx.x;
  const int gb = (int)(lin >> 4), rb = (int)(lin & 15);
  const int m0 = (gb * 8 + (rb & 7)) * 128;
  const int n0 = (rb >> 3) * 256;
  const int tid = threadIdx.x;
  const int wave = tid >> 6, lane = tid & 63;
  const int wr = wave >> 2, wc = wave & 3;          // 2x4 wave grid (64x64 each)
  const int lm = lane & 15, lq = lane >> 4;
  const int arow = tid >> 2, aq = (tid & 3) * 8;    // A staging: 8 fp32/thread
  const int brow = tid >> 1, bq = (tid & 1) * 16;   // B staging: 16 bf16/thread

  const float*   Xp = X + (size_t)(m0 + arow) * K + aq;
  const ushortT* Wp = W16 + (size_t)(n0 + brow) * K + bq;
  uint4* As_w = (uint4*)&As[arow * SA2 + aq];
  uint4* Bs_w = (uint4*)&Bs[brow * SA2 + bq];

  f32x4 acc[4][4];
#pragma unroll
  for (int i = 0; i < 4; i++)
#pragma unroll
    for (int j = 0; j < 4; j++) acc[i][j] = (f32x4){0.f, 0.f, 0.f, 0.f};

  float4 a0 = *(const float4*)(Xp);
  float4 a1 = *(const float4*)(Xp + 4);
  uint4 b0v = *(const uint4*)(Wp);
  uint4 b1v = *(const uint4*)(Wp + 8);

  for (int k0 = 0; k0 < K; k0 += 32) {
    __syncthreads();
    uint4 ao;
    ao.x = pk2bf(a0.x, a0.y); ao.y = pk2bf(a0.z, a0.w);
    ao.z = pk2bf(a1.x, a1.y); ao.w = pk2bf(a1.z, a1.w);
    As_w[0] = ao;
    Bs_w[0] = b0v;
    Bs_w[1] = b1v;
    if (k0 + 32 < K) {
      a0 = *(const float4*)(Xp + k0 + 32);
      a1 = *(const float4*)(Xp + k0 + 36);
      b0v = *(const uint4*)(Wp + k0 + 32);
      b1v = *(const uint4*)(Wp + k0 + 40);
    }
    __syncthreads();
    bf16x8 af[4], bfv[4];
#pragma unroll
    for (int mt = 0; mt < 4; mt++)
      af[mt] = *(const bf16x8*)&As[(wr * 64 + mt * 16 + lm) * SA2 + lq * 8];
#pragma unroll
    for (int nt = 0; nt < 4; nt++)
      bfv[nt] = *(const bf16x8*)&Bs[(wc * 64 + nt * 16 + lm) * SA2 + lq * 8];
#pragma unroll
    for (int mt = 0; mt < 4; mt++)
#pragma unroll
      for (int nt = 0; nt < 4; nt++)
        acc[mt][nt] = __builtin_amdgcn_mfma_f32_16x16x32_bf16(af[mt], bfv[nt], acc[mt][nt], 0, 0, 0);
  }
  float biasv[4], scv[4];
#pragma unroll
  for (int nt = 0; nt < 4; nt++) {
    const int C = n0 + wc * 64 + nt * 16 + lm;       // permuted col
    const int g = C & 3;
    biasv[nt] = bias[(g << 7) + (C >> 2)];           // original gate-major idx
    scv[nt] = (g == 2) ? K2C : K1C;
  }
#pragma unroll
  for (int mt = 0; mt < 4; mt++) {
#pragma unroll
    for (int nt = 0; nt < 4; nt++) {
      const int row0 = m0 + wr * 64 + mt * 16 + lq * 4;
      const int col = n0 + wc * 64 + nt * 16 + lm;
#pragma unroll
      for (int r = 0; r < 4; r++)
        Y16[(size_t)(row0 + r) * N + col] = (ushortT)f2bf((acc[mt][nt][r] + biasv[nt]) * scv[nt]);
    }
  }
}

// ------ audio/vision projection: fp32 input read + cvt in staging ----------
template <int KP, int KIN, int LOG2H>
__device__ __forceinline__ void gemm_xpf_impl(const float* __restrict__ X,
                                              const ushortT* __restrict__ B16,
                                              const float* __restrict__ bias,
                                              ushortT* __restrict__ Y16,
                                              ushortT* As, ushortT* Bs) {
  constexpr int SB = KP + 8;
  const int n0 = blockIdx.x * 128;
  const int m0 = blockIdx.y * 128;
  const int tid = threadIdx.x;
  const int wave = tid >> 6, lane = tid & 63;
  const int wr = wave >> 1, wc = wave & 1;
  const int lm = lane & 15, lq = lane >> 4;

  // stage X: fp32 -> bf16 with K-pad (4 cols per task)
  for (int idx = tid; idx < 128 * (KP / 4); idx += 256) {
    const int row = idx / (KP / 4), c0 = (idx % (KP / 4)) * 4;
    f4u v = {0.f, 0.f, 0.f, 0.f};
    const int rem = KIN - c0;
    const float* xr = X + (size_t)(m0 + row) * KIN + c0;
    if (rem >= 4) v = *(const f4u*)xr;
    else if (rem > 0) {
      v.x = xr[0];
      if (rem > 1) v.y = xr[1];
      if (rem > 2) v.z = xr[2];
    }
    uint2 pk;
    pk.x = pk2bf(v.x, v.y);
    pk.y = pk2bf(v.z, v.w);
    *(uint2*)&As[row * SB + c0] = pk;
  }
  // stage W (bf16, pre-permuted rows)
  for (int idx = tid; idx < 128 * (KP / 8); idx += 256) {
    const int row = idx / (KP / 8), sg = idx % (KP / 8);
    *(uint4*)&Bs[row * SB + sg * 8] = *(const uint4*)(B16 + (size_t)row * KP + sg * 8);
  }
  __syncthreads();

  constexpr int KC = KP / 32;
  f32x4 acc[4][4];
#pragma unroll
  for (int i = 0; i < 4; i++)
#pragma unroll
    for (int j = 0; j < 4; j++) acc[i][j] = (f32x4){0.f, 0.f, 0.f, 0.f};
#pragma unroll
  for (int ks = 0; ks < KC; ks++) {
    bf16x8 af[4], bfv[4];
#pragma unroll
    for (int mt = 0; mt < 4; mt++)
      af[mt] = *(const bf16x8*)&As[(wr * 64 + mt * 16 + lm) * SB + ks * 32 + lq * 8];
#pragma unroll
    for (int nt = 0; nt < 4; nt++)
      bfv[nt] = *(const bf16x8*)&Bs[(wc * 64 + nt * 16 + lm) * SB + ks * 32 + lq * 8];
#pragma unroll
    for (int mt = 0; mt < 4; mt++)
#pragma unroll
      for (int nt = 0; nt < 4; nt++)
        acc[mt][nt] = __builtin_amdgcn_mfma_f32_16x16x32_bf16(af[mt], bfv[nt], acc[mt][nt], 0, 0, 0);
  }
  float biasv[4], scv[4];
#pragma unroll
  for (int nt = 0; nt < 4; nt++) {
    const int C = n0 + wc * 64 + nt * 16 + lm;
    const int g = C & 3;
    biasv[nt] = bias[(g << LOG2H) + (C >> 2)];
    scv[nt] = (g == 2) ? K2C : K1C;
  }
#pragma unroll
  for (int mt = 0; mt < 4; mt++) {
#pragma unroll
    for (int nt = 0; nt < 4; nt++) {
      const int row0 = m0 + wr * 64 + mt * 16 + lq * 4;
      const int col = n0 + wc * 64 + nt * 16 + lm;
#pragma unroll
      for (int r = 0; r < 4; r++)
        Y16[(size_t)(row0 + r) * 256 + col] = (ushortT)f2bf((acc[mt][nt][r] + biasv[nt]) * scv[nt]);
    }
  }
}

__global__ __launch_bounds__(256) void gemm_avf_k(const float* __restrict__ audio,
                                                  const ushortT* __restrict__ WA16,
                                                  const float* __restrict__ b_a,
                                                  ushortT* __restrict__ xpa,
                                                  const float* __restrict__ vision,
                                                  const ushortT* __restrict__ WV16,
                                                  const float* __restrict__ b_v,
                                                  ushortT* __restrict__ xpv) {
  __shared__ __align__(16) ushortT As[128 * 104];
  __shared__ __align__(16) ushortT Bs[128 * 104];
  if (blockIdx.z == 0) gemm_xpf_impl<96, 74, 6>(audio, WA16, b_a, xpa, As, Bs);
  else gemm_xpf_impl<64, 35, 6>(vision, WV16, b_v, xpv, As, Bs);
}

// --------------------- batched-MFMA LSTM recurrence (v6) --------------------
// v5 structure + pre-scaled gates (bare v_exp_f32), packed-f32 activation
// arithmetic, v_cvt_pk_bf16_f32 h-stores.
__device__ __forceinline__ void bar_lgkm() {
  asm volatile("s_waitcnt lgkmcnt(0)" ::: "memory");
  __builtin_amdgcn_sched_barrier(0);
  __builtin_amdgcn_s_barrier();
  __builtin_amdgcn_sched_barrier(0);
}

template <int H, int COFF, int CW>
__device__ __forceinline__ void recur_impl6(const ushortT* __restrict__ xp,   // [b][t][col][4]
                                            const ushortT* __restrict__ Whh, // [4H][H] prescaled
                                            ushortT* __restrict__ z,         // [B*T][256]
                                            int bblk, char* smem_) {
  constexpr int KC = H / 32;
  constexpr int C4H = 4 * H;
  constexpr int HP = H + 8;              // h-ring row stride
  constexpr int RING = 6;
  constexpr int CRB = H / 8;             // 16B runs per z row
  constexpr int FPT = (64 * CRB) / 512;  // flush uint4 per thread
  constexpr int RS = 256 * C4H;          // per-batch stride (ushorts)
  ushortT* hbuf = (ushortT*)smem_;       // [RING][16][HP]
  const int tid = threadIdx.x;
  const int s = tid >> 6, lane = tid & 63;
  const int lm = lane & 15, lq = lane >> 4;
  const int b0 = bblk * 16;
  const bool comp = (s < CW);
  const ushortT* xb = xp + (size_t)(b0 + lq * 4) * RS + (s * 16 + lm) * 4;

  bf16x8 bw[4][KC];
  if (comp) {
#pragma unroll
    for (int g = 0; g < 4; g++)
#pragma unroll
      for (int kc = 0; kc < KC; kc++) {
        const int n = g * H + s * 16 + lm;
        bw[g][kc] = *(const bf16x8*)(Whh + (size_t)n * H + kc * 32 + lq * 8);
      }
  }
  for (int i = tid; i < 16 * HP; i += 512) hbuf[(RING - 1) * 16 * HP + i] = 0;

  uint2 gA[4], gB[4];
  if (comp) {
#pragma unroll
    for (int r = 0; r < 4; r++) {
      gA[r] = *(const uint2*)(xb + (size_t)r * RS);
      gB[r] = *(const uint2*)(xb + (size_t)r * RS + C4H);
    }
  }
  float cst[4] = {0.f, 0.f, 0.f, 0.f};
  __syncthreads();

  auto step = [&](int t, uint2 (&gCur)[4]) {
    // ---- flush h-ring to z (4 rows, wide stores), off the critical path ----
    if (t >= 4 && (t & 3) == 0) {
      const int t0 = t - 4;
#pragma unroll
      for (int i = 0; i < FPT; i++) {
        const int q = i * 512 + tid;
        const int m = q / (4 * CRB), j = (q / CRB) & 3, cr = q % CRB;
        const uint4 v = *(const uint4*)&hbuf[((t0 + j) % RING) * 16 * HP + m * HP + cr * 8];
        *(uint4*)&z[((size_t)(b0 + m) * 256 + t0 + j) * 256 + COFF + cr * 8] = v;
      }
    }
    if (comp) {
      // ---- extract gate addends (prescaled), re-issue loads for t+2 ----
      f32x4 ad0, ad1, ad2, ad3;
#pragma unroll
      for (int r = 0; r < 4; r++) {
        const unsigned int w0 = gCur[r].x, w1 = gCur[r].y;
        ad0[r] = __uint_as_float(w0 << 16);
        ad1[r] = __uint_as_float(w0 & 0xffff0000u);
        ad2[r] = __uint_as_float(w1 << 16);
        ad3[r] = __uint_as_float(w1 & 0xffff0000u);
      }
      const int tn = (t + 2 < 256) ? t + 2 : 255;
#pragma unroll
      for (int r = 0; r < 4; r++)
        gCur[r] = *(const uint2*)(xb + (size_t)r * RS + (size_t)tn * C4H);
      // ---- gate GEMM ----
      const ushortT* hb = &hbuf[((t + RING - 1) % RING) * 16 * HP + lm * HP];
      bf16x8 af[KC];
#pragma unroll
      for (int kc = 0; kc < KC; kc++) af[kc] = *(const bf16x8*)(hb + kc * 32 + lq * 8);
      f32x4 acc[4];
#pragma unroll
      for (int g = 0; g < 4; g++) acc[g] = (f32x4){0.f, 0.f, 0.f, 0.f};
#pragma unroll
      for (int kc = 0; kc < KC; kc++)
#pragma unroll
        for (int g = 0; g < 4; g++)
          acc[g] = __builtin_amdgcn_mfma_f32_16x16x32_bf16(af[kc], bw[g][kc], acc[g], 0, 0, 0);
      // ---- activations: packed f32 arithmetic, bare exp2 ----
      ushortT* hw = &hbuf[(t % RING) * 16 * HP];
      const int col = s * 16 + lm;
#pragma unroll
      for (int p = 0; p < 2; p++) {
        const int r0 = 2 * p, r1 = 2 * p + 1;
        f32x2 iv = { acc[0][r0] + ad0[r0], acc[0][r1] + ad0[r1] };
        f32x2 fv = { acc[1][r0] + ad1[r0], acc[1][r1] + ad1[r1] };
        f32x2 gv = { acc[2][r0] + ad2[r0], acc[2][r1] + ad2[r1] };
        f32x2 ov = { acc[3][r0] + ad3[r0], acc[3][r1] + ad3[r1] };
        f32x2 ei = { exp2i(iv.x), exp2i(iv.y) };
        f32x2 ef = { exp2i(fv.x), exp2i(fv.y) };
        f32x2 eg = { exp2i(gv.x), exp2i(gv.y) };
        f32x2 pi = ei + 1.f, pf = ef + 1.f, pg = eg + 1.f;
        f32x2 t1 = pi * pg;
        f32x2 cst2 = { cst[r0], cst[r1] };
        f32x2 num = cst2 * t1 + (1.f - eg) * pf;
        f32x2 den = pf * t1;
        f32x2 cc = { num.x * __builtin_amdgcn_rcpf(den.x),
                     num.y * __builtin_amdgcn_rcpf(den.y) };
        cst[r0] = cc.x; cst[r1] = cc.y;
        f32x2 eo = { exp2i(ov.x), exp2i(ov.y) };
        f32x2 ec = { exp2i(cc.x * K2C), exp2i(cc.y * K2C) };
        f32x2 hn = 1.f - ec;
        f32x2 hd = (eo + 1.f) * (ec + 1.f);
        const float h0 = hn.x * __builtin_amdgcn_rcpf(hd.x);
        const float h1 = hn.y * __builtin_amdgcn_rcpf(hd.y);
        hw[(lq * 4 + r0) * HP + col] = (ushortT)cvtbf(h0);
        hw[(lq * 4 + r1) * HP + col] = (ushortT)cvtbf(h1);
      }
    }
    bar_lgkm();
  };

  for (int t = 0; t < 256; t += 2) {
    step(t, gA);
    step(t + 1, gB);
  }
  {  // final flush: z rows 252..255
    const int t0 = 252;
#pragma unroll
    for (int i = 0; i < FPT; i++) {
      const int q = i * 512 + tid;
      const int m = q / (4 * CRB), j = (q / CRB) & 3, cr = q % CRB;
      const uint4 v = *(const uint4*)&hbuf[((t0 + j) % RING) * 16 * HP + m * HP + cr * 8];
      *(uint4*)&z[((size_t)(b0 + m) * 256 + t0 + j) * 256 + COFF + cr * 8] = v;
    }
  }
}

__global__ __launch_bounds__(512, 1) void recur6_k(const ushortT* __restrict__ xpt,
                                                   const ushortT* __restrict__ xpa,
                                                   const ushortT* __restrict__ xpv_,
                                                   const ushortT* __restrict__ Wt,
                                                   const ushortT* __restrict__ Wa,
                                                   const ushortT* __restrict__ Wv,
                                                   ushortT* __restrict__ z) {
  extern __shared__ char smem[];
  const int bid = blockIdx.x;
  if (bid < 16) recur_impl6<128, 128, 8>(xpt, Wt, z, bid, smem);
  else if (bid < 32) recur_impl6<64, 0, 4>(xpa, Wa, z, bid - 16, smem);
  else recur_impl6<64, 64, 4>(xpv_, Wv, z, bid - 32, smem);
}

// ------------------------ fusion (+ fused epilogue) -------------------------
__global__ __launch_bounds__(192) void fusion_k(const ushortT* __restrict__ z,
                                                const float* __restrict__ W1,
                                                const float* __restrict__ b1,
                                                const float* __restrict__ w2a,
                                                const float* __restrict__ w2b,
                                                const float* __restrict__ w2c,
                                                const float* __restrict__ b2,
                                                const float* __restrict__ fw,
                                                float* __restrict__ s_acc,
                                                float* __restrict__ sumsq,
                                                unsigned int* __restrict__ cnt,
                                                float* __restrict__ out) {
  __shared__ __align__(16) float zs[256 * 36];
  __shared__ float red[12];
  __shared__ unsigned int done_s;
  const int tid = threadIdx.x;
  const int b = blockIdx.x >> 3;
  const int t0 = (blockIdx.x & 7) * 32;
  const ushortT* zb = z + (size_t)b * 65536;
  float sq = 0.0f;
  for (int idx = tid; idx < 33 * 64; idx += 192) {  // uint2 z loads (4 elems)
    const int row = idx >> 6, kq = idx & 63;
    int t = t0 + row; if (t >= 256) t -= 256;
    const uint2 v = *(const uint2*)(zb + t * 256 + kq * 4);
    const float f0 = __uint_as_float(v.x << 16);
    const float f1 = __uint_as_float(v.x & 0xffff0000u);
    const float f2 = __uint_as_float(v.y << 16);
    const float f3 = __uint_as_float(v.y & 0xffff0000u);
    const int base = kq * 4 * 36 + row;
    zs[base] = f0; zs[base + 36] = f1; zs[base + 72] = f2; zs[base + 108] = f3;
    if (row < 32) sq += f0 * f0 + f1 * f1 + f2 * f2 + f3 * f3;
  }
  __syncthreads();
  const int dg = tid >> 3;
  const int rg = tid & 7;
  const float* w1p = W1 + dg * 256;
  const float* w2ap = w2a + dg * 256;
  const float* w2bp = w2b + dg * 256;
  float aa[4] = {}, ab1[4] = {}, ab2[4] = {};
  for (int k = 0; k < 256; k += 4) {
    const float4 w1v4  = *(const float4*)(w1p + k);
    const float4 w21v4 = *(const float4*)(w2ap + k);
    const float4 w22v4 = *(const float4*)(w2bp + k);
#define FUS_STEP(J, W1C, W21C, W22C)                                   \
    {                                                                  \
      const float* zr = &zs[(k + J) * 36 + (rg << 2)];                 \
      const float4 za = *(const float4*)zr;                            \
      const float z4 = zr[4];                                          \
      aa[0] += za.x * (W1C); aa[1] += za.y * (W1C);                    \
      aa[2] += za.z * (W1C); aa[3] += za.w * (W1C);                    \
      ab1[0] += za.x * (W21C); ab1[1] += za.y * (W21C);                \
      ab1[2] += za.z * (W21C); ab1[3] += za.w * (W21C);                \
      ab2[0] += za.y * (W22C); ab2[1] += za.z * (W22C);                \
      ab2[2] += za.w * (W22C); ab2[3] += z4 * (W22C);                  \
    }
    FUS_STEP(0, w1v4.x, w21v4.x, w22v4.x)
    FUS_STEP(1, w1v4.y, w21v4.y, w22v4.y)
    FUS_STEP(2, w1v4.z, w21v4.z, w22v4.z)
    FUS_STEP(3, w1v4.w, w21v4.w, w22v4.w)
#undef FUS_STEP
  }
  const float b1v = b1[dg];
  const float b2v = b2[dg] + w2c[dg];
  const float fwv = fw[dg];
  float s = 0.0f;
#pragma unroll
  for (int i = 0; i < 4; i++) {
    const float a  = aa[i] + b1v;
    const float bb = ab1[i] + ab2[i] + b2v;
    s += a * bb;
  }
  s *= fwv;
#pragma unroll
  for (int off = 32; off > 0; off >>= 1) {
    s  += __shfl_down(s, off);
    sq += __shfl_down(sq, off);
  }
  const int wid = tid >> 6;
  if ((tid & 63) == 0) { red[wid * 2] = s; red[wid * 2 + 1] = sq; }
  __syncthreads();
  if (tid == 0) {
    atomicAdd(&s_acc[b], red[0] + red[2] + red[4]);
    atomicAdd(&sumsq[b], red[1] + red[3] + red[5]);
    __threadfence();
    done_s = atomicAdd(cnt, 1u);
  }
  __syncthreads();
  if (done_s == 2047) {  // last block: fused epilogue
    __threadfence();
    float sl = 0.f;
    for (int i = tid; i < 256; i += 192) {
      const float sa = __hip_atomic_load(&s_acc[i], __ATOMIC_RELAXED, __HIP_MEMORY_SCOPE_AGENT);
      const float sb = __hip_atomic_load(&sumsq[i], __ATOMIC_RELAXED, __HIP_MEMORY_SCOPE_AGENT);
      out[i] = sa * (1.0f / 256.0f);
      sl += sqrtf(sb);
    }
#pragma unroll
    for (int off = 32; off > 0; off >>= 1) sl += __shfl_down(sl, off);
    if ((tid & 63) == 0) red[6 + (tid >> 6)] = sl;
    __syncthreads();
    if (tid == 0) out[256] = (red[6] + red[7] + red[8]) * (1.0f / 256.0f);
  }
}

// ---------------------------------------------------------------------------
extern "C" void kernel_launch(void* const* d_in, const int* in_sizes, int n_in,
                              void* d_out, int out_size, void* d_ws, size_t ws_size,
                              hipStream_t stream) {
  const float* text   = (const float*)d_in[0];
  const float* audio  = (const float*)d_in[1];
  const float* vision = (const float*)d_in[2];
  const float* Wih_t  = (const float*)d_in[3];
  const float* Whh_t  = (const float*)d_in[4];
  const float* b_t    = (const float*)d_in[5];
  const float* Wih_a  = (const float*)d_in[6];
  const float* Whh_a  = (const float*)d_in[7];
  const float* b_a    = (const float*)d_in[8];
  const float* Wih_v  = (const float*)d_in[9];
  const float* Whh_v  = (const float*)d_in[10];
  const float* b_v    = (const float*)d_in[11];
  const float* W1     = (const float*)d_in[12];
  const float* b1     = (const float*)d_in[13];
  const float* W2     = (const float*)d_in[14];
  const float* b2     = (const float*)d_in[15];
  const float* fw     = (const float*)d_in[16];

  // workspace layout (bf16 elems unless noted)
  ushortT* xpt = (ushortT*)d_ws;               // 65536*512 ([b][t][col][4])
  ushortT* xpa = xpt + (size_t)33554432;       // 65536*256
  ushortT* xpv = xpa + (size_t)16777216;       // 65536*256
  ushortT* z16 = xpv + (size_t)16777216;       // 65536*256
  float* s_acc = (float*)(z16 + (size_t)16777216);  // 256 f32
  float* sumsq = s_acc + 256;                       // 256 f32
  ushortT* WhhT16 = (ushortT*)(sumsq + 256);   // 512*128 (prescaled)
  ushortT* WhhA16 = WhhT16 + 65536;            // 256*64  (prescaled)
  ushortT* WhhV16 = WhhA16 + 16384;            // 256*64  (prescaled)
  float* w2a = (float*)(WhhV16 + 16384);       // 24*256 f32
  float* w2b = w2a + 6144;                     // 24*256 f32
  float* w2c = w2b + 6144;                     // 24 f32
  unsigned int* cnt = (unsigned int*)(w2c + 24);
  // scratch aliased into z16 (consumed by gemms before recur writes z):
  ushortT* Wt768 = z16;                        // 512*768 (row-permuted)
  ushortT* WA16  = Wt768 + 393216;             // 256*96  (row-permuted)
  ushortT* WV16  = WA16 + 24576;               // 256*64  (row-permuted)

  prep_k<<<2130, 256, 0, stream>>>(Wih_t, Whh_t, Wih_a, Whh_a, Wih_v, Whh_v, W2,
                                   Wt768, WhhT16, WA16, WhhA16, WV16, WhhV16,
                                   w2a, w2b, w2c, s_acc, sumsq, cnt);

  gemm_text2_k<<<1024, 512, 0, stream>>>(text, Wt768, b_t, xpt);
  gemm_avf_k<<<dim3(2, 512, 2), 256, 0, stream>>>(audio, WA16, b_a, xpa,
                                                  vision, WV16, b_v, xpv);
  // dynamic LDS: h-ring only; text variant needs 6*16*136*2 = 26112 B
  recur6_k<<<48, 512, 26112, stream>>>(xpt, xpa, xpv, WhhT16, WhhA16, WhhV16, z16);
  fusion_k<<<2048, 192, 0, stream>>>(z16, W1, b1, w2a, w2b, w2c, b2, fw,
                                     s_acc, sumsq, cnt, (float*)d_out);
}